// Round 10
// baseline (142.995 us; speedup 1.0000x reference)
//
#include <hip/hip_runtime.h>

// GINConv: out = MLP((1+eps)*x + neighbor_sum), MLP = 64->128 relu -> 64, fp32.
// Round 24: R23 WIN (146.8->141.5): LDS 79->30KB lifted part2 occ 27->41%,
// dur 55.6->46.6 as predicted. New ceiling identified: phase B carries only
// N/8=6250 waves (8 nodes/wave) = 24.4 waves/CU vs 32 capacity -- the GRID
// is the occupancy limit now, not LDS. VALUBusy 46% and rising.
// THIS ROUND: 1024-thread part2 blocks, 4 nodes/wave. Same 782 blocks ->
// 16 waves/block -> 12500 waves = 48.8/CU demanded -> capacity-limited
// (2 blocks/CU x 16 waves = 32 waves = 100%), ~1.5 passes. part1/prep
// untouched. MFMA tail: 4 tiles x 4 waves (GEMM1 2 cols/wave, GEMM2 1);
// A-fragments loaded redundantly per tile (cheap LDS). launch_bounds(1024,8).
// Prediction: part2 occ 41->70-90%, dur 46.6->30-36, total ->125-132.
// If occ rises but time doesn't: outstanding-miss limit -> near-floor
// (fixed ~45us harness re-poison + part1 ~25 + part2 ~30 is structural).
// Invariants: MFMA layouts HW-verified; weights direct-from-global (R23);
// hbuf aliases pre_lds after fragment loads (R23); no fp LDS atomics (R19);
// ~200K global atomics (R17); part1 sorted-coalesced scatter (R21);
// self-loops verified; dummy = zeroed xh row N; CSR/scatter fallbacks intact.

#define D 64
#define H 128
#define MPW 8            // nodes per wave in the fallback VALU MLP
#define REGSH 6          // region = 64 nodes (v >> 6)
#define REGSZ 64
#define P1_BLOCKS 256
#define EVBUF_SZ 6400    // LDS event buffer in part1 (2*EPB must fit)
#define NR_MAX 1024
#define NCAP 96          // per-node LDS list capacity (Poisson(32): safe)
#define PSTR 68          // pre_lds row stride in floats (16B-aligned, 2-way)

typedef __attribute__((ext_vector_type(8))) short short8;   // 8 bf16 (4 VGPRs)
typedef __attribute__((ext_vector_type(4))) float float4v;  // 4 fp32

__device__ __forceinline__ float lane_bcast(float v, int l) {
    return __uint_as_float(__builtin_amdgcn_readlane(__float_as_uint(v), l));
}

__device__ __forceinline__ unsigned short f2bf(float f) {
    unsigned int u = __float_as_uint(f);
    u = (u + (((u >> 16) & 1u) + 0x7fffu)) >> 16;
    return (unsigned short)u;
}

__device__ __forceinline__ void bf2_acc(unsigned int u, float& a, float& b) {
    a += __uint_as_float(u << 16);            // low ushort  = feature 2h
    b += __uint_as_float(u & 0xffff0000u);    // high ushort = feature 2h+1
}

__global__ void zero_int_kernel(int* __restrict__ p, int n) {
    int i = blockIdx.x * blockDim.x + threadIdx.x;
    if (i < n) p[i] = 0;
}

__global__ void zero_f_kernel(float* __restrict__ p, int n) {
    int i = blockIdx.x * blockDim.x + threadIdx.x;
    if (i < n) p[i] = 0.0f;
}

// prep (tiny): init region cursors, zero dummy row N, swizzle weights.
__global__ void prep_kernel(unsigned int* __restrict__ xh2, int npairs,
                            int* __restrict__ cursor, int NR, int CAPB,
                            const float* __restrict__ W1,
                            const float* __restrict__ W2,
                            unsigned short* __restrict__ wsW1,
                            unsigned short* __restrict__ wsW2) {
    int i = blockIdx.x * blockDim.x + threadIdx.x;
    if (i < NR) cursor[i] = i * CAPB;
    if (i < 32) xh2[npairs + i] = 0;    // dummy row N (zero target)
    if (i < 8192) {
        int j = i & 7, ln = (i >> 3) & 63;
        int q = (ln >> 4) & 3;
        int tt1 = (i >> 9) & 7, s1 = i >> 12;
        wsW1[i] = f2bf(W1[(s1 * 32 + q * 8 + j) * H + tt1 * 16 + (ln & 15)]);
        int tt2 = (i >> 9) & 3, s2 = i >> 11;
        wsW2[i] = f2bf(W2[(s2 * 32 + q * 8 + j) * D + tt2 * 16 + (ln & 15)]);
    }
}

// ---- part1: x->bf16 cast prologue + region partition with sorted,
// coalesced output writes (R21-proven).
__global__ __launch_bounds__(256) void part1_kernel(
    const int* __restrict__ src, const int* __restrict__ dst,
    int* __restrict__ cursor, unsigned int* __restrict__ evarr,
    const float* __restrict__ x, unsigned int* __restrict__ xh2, int npairs,
    int E, int N, int NR, int CAPB, int EPB)
{
    __shared__ unsigned int evbuf[EVBUF_SZ];        // 25.6KB raw events
    __shared__ unsigned int sortbuf[EVBUF_SZ];      // 25.6KB region-sorted
    __shared__ unsigned short tickbuf[EVBUF_SZ];    // 12.8KB per-event rank
    __shared__ int hist[NR_MAX];                    // 4KB per-region count
    __shared__ int lbase[NR_MAX];                   // 4KB local prefix base
    __shared__ int gbase[NR_MAX];                   // 4KB global chunk base
    __shared__ int scanw[256];                      // 1KB scan workspace
    int t = threadIdx.x;

    // cast prologue: grid-stride over bf16 pairs (consumer is part2, later)
    int gstride = gridDim.x * 256;
    for (int i = blockIdx.x * 256 + t; i < npairs; i += gstride) {
        float2 v = *(const float2*)(x + (size_t)i * 2);
        unsigned int a = __float_as_uint(v.x);
        unsigned int b = __float_as_uint(v.y);
        a = (a + (((a >> 16) & 1u) + 0x7fffu)) >> 16;
        b = (b + (((b >> 16) & 1u) + 0x7fffu)) >> 16;
        xh2[i] = a | (b << 16);
    }

    for (int b = t; b < NR; b += 256) hist[b] = 0;
    __syncthreads();

    // pass 1: load events, LDS histogram with per-event ticket
    int e0 = blockIdx.x * EPB;
    int ne = E - e0; if (ne > EPB) ne = EPB; if (ne < 0) ne = 0;
    for (int i = t; i < ne; i += 256) {
        int s = src[e0 + i], d = dst[e0 + i];
        s = (s < 0) ? 0 : ((s >= N) ? N - 1 : s);
        d = (d < 0) ? 0 : ((d >= N) ? N - 1 : d);
        unsigned int ev0 = ((unsigned int)s << 16) | (unsigned int)d;
        unsigned int ev1 = ((unsigned int)d << 16) | (unsigned int)s;
        int k0 = atomicAdd(&hist[s >> REGSH], 1);
        int k1 = atomicAdd(&hist[d >> REGSH], 1);
        evbuf[2 * i]     = ev0; tickbuf[2 * i]     = (unsigned short)k0;
        evbuf[2 * i + 1] = ev1; tickbuf[2 * i + 1] = (unsigned short)k1;
    }
    __syncthreads();

    // exclusive prefix scan: hist -> lbase (4 entries per thread + block scan)
    {
        int i0 = t * 4;
        int h0 = (i0 + 0 < NR) ? hist[i0 + 0] : 0;
        int h1 = (i0 + 1 < NR) ? hist[i0 + 1] : 0;
        int h2 = (i0 + 2 < NR) ? hist[i0 + 2] : 0;
        int h3 = (i0 + 3 < NR) ? hist[i0 + 3] : 0;
        int s4 = h0 + h1 + h2 + h3;
        scanw[t] = s4;
        __syncthreads();
        for (int off = 1; off < 256; off <<= 1) {
            int u = (t >= off) ? scanw[t - off] : 0;
            __syncthreads();
            scanw[t] += u;
            __syncthreads();
        }
        int run = scanw[t] - s4;   // exclusive base for this thread's chunk
        if (i0 + 0 < NR) { lbase[i0 + 0] = run; run += h0; }
        if (i0 + 1 < NR) { lbase[i0 + 1] = run; run += h1; }
        if (i0 + 2 < NR) { lbase[i0 + 2] = run; run += h2; }
        if (i0 + 3 < NR) { lbase[i0 + 3] = run; run += h3; }
    }

    // reserve: one global atomic per nonzero region
    for (int b = t; b < NR; b += 256) {
        int c = hist[b];
        gbase[b] = c ? atomicAdd(&cursor[b], c) : 0;
    }
    __syncthreads();

    // LDS reorder: sortbuf holds events grouped by region
    int nev = 2 * ne;
    for (int i = t; i < nev; i += 256) {
        unsigned int ev = evbuf[i];
        int reg = (int)(ev >> (16 + REGSH));
        sortbuf[lbase[reg] + (int)tickbuf[i]] = ev;
    }
    __syncthreads();

    // coalesced global write: consecutive i -> consecutive addr per region run
    for (int i = t; i < nev; i += 256) {
        unsigned int ev = sortbuf[i];
        int reg = (int)(ev >> (16 + REGSH));
        int addr = gbase[reg] + (i - lbase[reg]);
        if (addr < (reg + 1) * CAPB) evarr[addr] = ev;
    }
}

// ---- part2_fused v4: 1024 threads, 16 waves, 4 nodes/wave. Phase A
// (bucket, int atomics) + Phase B (register gather) + MFMA MLP (4 tiles x
// 4 waves; weights direct from global; hbuf aliases pre_lds).
// LDS ~30KB, 2 blocks/CU = 32 waves/CU.
__global__ __launch_bounds__(1024, 8) void part2_fused(
    const unsigned int* __restrict__ evarr, const int* __restrict__ cursor,
    const unsigned short* __restrict__ xh, const float* __restrict__ x,
    const float* __restrict__ epsp,
    const unsigned short* __restrict__ wsW1,
    const unsigned short* __restrict__ wsW2,
    const float* __restrict__ b1, const float* __restrict__ b2,
    float* __restrict__ y, int N, int CAPB)
{
    __shared__ unsigned short nbuf[REGSZ * NCAP + 32];  // 12.1KB (+pad tail)
    __shared__ int scnt[REGSZ];                         // 256B
    __shared__ float pre_lds[REGSZ * PSTR];             // 17.4KB; hbuf aliases
    int t = threadIdx.x;
    int b = blockIdx.x;
    if (t < REGSZ) scnt[t] = 0;
    __syncthreads();

    int base = b * CAPB;
    int count = cursor[b] - base;
    if (count < 0) count = 0;
    if (count > CAPB) count = CAPB;

    // Phase A: bucket into per-node lists (int ticket + plain ds_write)
    for (int i = t; i < count; i += 1024) {
        unsigned int ev = evarr[base + i];
        int row = (int)((ev >> 16) & (REGSZ - 1));
        int k = atomicAdd(&scnt[row], 1);
        if (k < NCAP) nbuf[row * NCAP + k] = (unsigned short)(ev & 0xffffu);
    }
    __syncthreads();

    // Phase B: 16 waves x 4 nodes, register accumulation -> pre_lds
    int wave = t >> 6, lane = t & 63;
    int r = lane >> 5;            // row slot 0..1
    int h = lane & 31;            // feature pair 2h, 2h+1
    float e1 = 1.0f + epsp[0];

    for (int k = 0; k < 4; ++k) {
        int n = wave * 4 + k;
        int v = b * REGSZ + n;
        int m = (v < N) ? scnt[n] : 0;
        m = (m > NCAP) ? NCAP : m;
        float f0 = 0.0f, f1 = 0.0f;
        for (int j = 0; j < m; j += 32) {
            int cc[16];
#pragma unroll
            for (int q = 0; q < 16; ++q) {
                int ii = j + 2 * q + r;
                int c = (int)nbuf[n * NCAP + ii];   // in-bounds via +32 pad
                cc[q] = (ii < m) ? c : N;           // dummy zero row past degree
            }
            unsigned int u[16];
#pragma unroll
            for (int q = 0; q < 16; ++q)
                u[q] = *(const unsigned int*)(xh + (size_t)cc[q] * D + 2 * h);
#pragma unroll
            for (int q = 0; q < 16; ++q) bf2_acc(u[q], f0, f1);
        }
        f0 += __shfl_xor(f0, 32, 64);
        f1 += __shfl_xor(f1, 32, 64);
        if (r == 0) {
            float2 sv = make_float2(0.0f, 0.0f);
            if (v < N) sv = *(const float2*)(x + (size_t)v * D + 2 * h);
            pre_lds[n * PSTR + 2 * h]     = f0 + e1 * sv.x;
            pre_lds[n * PSTR + 2 * h + 1] = f1 + e1 * sv.y;
        }
    }
    __syncthreads();

    // ---- MFMA MLP: tile p = wave>>2 (16 nodes), quarter sub = wave&3.
    int p = wave >> 2, sub = wave & 3;
    int quad = lane >> 4, lm = lane & 15;
    int row0 = p * 16 + lm;               // node-in-region this lane supplies

    short8 a1f[2];
#pragma unroll
    for (int s = 0; s < 2; ++s) {
        const float* rp = &pre_lds[row0 * PSTR + s * 32 + quad * 8];
        float4v p0 = *(const float4v*)rp;
        float4v p1 = *(const float4v*)(rp + 4);
        short8 a;
        a[0] = (short)f2bf(p0[0]); a[1] = (short)f2bf(p0[1]);
        a[2] = (short)f2bf(p0[2]); a[3] = (short)f2bf(p0[3]);
        a[4] = (short)f2bf(p1[0]); a[5] = (short)f2bf(p1[1]);
        a[6] = (short)f2bf(p1[2]); a[7] = (short)f2bf(p1[3]);
        a1f[s] = a;
    }
    __syncthreads();    // all pre_lds reads done -> safe to alias as hbuf

    unsigned short* hbuf = (unsigned short*)pre_lds;  // 16KB used of 17.4KB

    // GEMM1: this wave computes h-columns tt = sub*2 .. sub*2+1
    float4v acc1[2];
#pragma unroll
    for (int i = 0; i < 2; ++i) {
        int tt = sub * 2 + i;
        float bb = b1[tt * 16 + lm];
        float4v c = {bb, bb, bb, bb};
#pragma unroll
        for (int s = 0; s < 2; ++s) {
            short8 bw = *(const short8*)&wsW1[((s * 8 + tt) * 64 + lane) * 8];
            c = __builtin_amdgcn_mfma_f32_16x16x32_bf16(a1f[s], bw, c, 0, 0, 0);
        }
        acc1[i] = c;
    }

    unsigned short* hb = &hbuf[p * 16 * H];
#pragma unroll
    for (int i = 0; i < 2; ++i) {
        int tt = sub * 2 + i;
#pragma unroll
        for (int rr = 0; rr < 4; ++rr) {
            float hv = fmaxf(acc1[i][rr], 0.0f);
            hb[(quad * 4 + rr) * H + tt * 16 + lm] = f2bf(hv);
        }
    }
    __syncthreads();

    short8 a2[4];
#pragma unroll
    for (int s = 0; s < 4; ++s)
        a2[s] = *(const short8*)&hb[lm * H + s * 32 + quad * 8];

    // GEMM2: this wave computes y-column tt = sub
    int v0t = b * REGSZ + p * 16;
    {
        int tt = sub;
        float bb = b2[tt * 16 + lm];
        float4v c = {bb, bb, bb, bb};
#pragma unroll
        for (int s = 0; s < 4; ++s) {
            short8 bw = *(const short8*)&wsW2[((s * 4 + tt) * 64 + lane) * 8];
            c = __builtin_amdgcn_mfma_f32_16x16x32_bf16(a2[s], bw, c, 0, 0, 0);
        }
#pragma unroll
        for (int rr = 0; rr < 4; ++rr) {
            int v = v0t + quad * 4 + rr;
            if (v < N) y[(size_t)v * D + tt * 16 + lm] = c[rr];
        }
    }
}

// ================= CSR machinery (fallback paths, fp32) =================

__global__ void count_kernel(const int* __restrict__ ei, int* __restrict__ deg,
                             int twoE, int N) {
    int i = blockIdx.x * blockDim.x + threadIdx.x;
    if (i < twoE) {
        int v = ei[i];
        v = (v < 0) ? 0 : ((v >= N) ? N - 1 : v);
        atomicAdd(&deg[v], 1);
    }
}

__global__ __launch_bounds__(256) void scan_part1(const int* __restrict__ deg,
                                                  int* __restrict__ bsum, int n) {
    __shared__ int red[256];
    int t = threadIdx.x;
    int i = blockIdx.x * 256 + t;
    red[t] = (i < n) ? deg[i] : 0;
    __syncthreads();
    for (int off = 128; off > 0; off >>= 1) {
        if (t < off) red[t] += red[t + off];
        __syncthreads();
    }
    if (t == 0) bsum[blockIdx.x] = red[0];
}

__global__ __launch_bounds__(256) void scan_part2(const int* __restrict__ bsum,
                                                  int* __restrict__ boff,
                                                  int* __restrict__ rowstart_n, int nb) {
    __shared__ int s[256];
    int t = threadIdx.x;
    int v = (t < nb) ? bsum[t] : 0;
    s[t] = v;
    __syncthreads();
    for (int off = 1; off < 256; off <<= 1) {
        int u = (t >= off) ? s[t - off] : 0;
        __syncthreads();
        s[t] += u;
        __syncthreads();
    }
    if (t < nb) boff[t] = s[t] - v;
    if (t == 255) *rowstart_n = s[255];
}

__global__ __launch_bounds__(256) void scan_part3(const int* __restrict__ deg,
                                                  const int* __restrict__ boff,
                                                  int* __restrict__ rowstart,
                                                  int* __restrict__ cursor, int n) {
    __shared__ int s[256];
    int t = threadIdx.x;
    int i = blockIdx.x * 256 + t;
    int v = (i < n) ? deg[i] : 0;
    s[t] = v;
    __syncthreads();
    for (int off = 1; off < 256; off <<= 1) {
        int u = (t >= off) ? s[t - off] : 0;
        __syncthreads();
        s[t] += u;
        __syncthreads();
    }
    if (i < n) {
        int r = boff[blockIdx.x] + s[t] - v;
        rowstart[i] = r;
        cursor[i] = r;
    }
}

__global__ __launch_bounds__(256) void scan_single(const int* __restrict__ deg,
                                                   int* __restrict__ rowstart,
                                                   int* __restrict__ cursor,
                                                   int n, int chunk) {
    __shared__ int psum[256];
    int t = threadIdx.x;
    int lo = t * chunk;
    int hi = lo + chunk; if (hi > n) hi = n;
    int s = 0;
    for (int i = lo; i < hi; ++i) s += deg[i];
    psum[t] = s;
    __syncthreads();
    for (int off = 1; off < 256; off <<= 1) {
        int v = (t >= off) ? psum[t - off] : 0;
        __syncthreads();
        psum[t] += v;
        __syncthreads();
    }
    int run = (t == 0) ? 0 : psum[t - 1];
    for (int i = lo; i < hi; ++i) {
        int d = deg[i];
        rowstart[i] = run;
        cursor[i] = run;
        run += d;
    }
    if (t == 255) rowstart[n] = psum[255];
}

__global__ __launch_bounds__(256) void fill_xcd(
    const int* __restrict__ src, const int* __restrict__ dst,
    int* __restrict__ cursor, int* __restrict__ col,
    int E, int N, int npg)
{
    int grp = blockIdx.x & 7;
    int slice = blockIdx.x >> 3;
    int lo = grp * npg;
    int hi = lo + npg; if (hi > N) hi = N;
    int stride = (gridDim.x >> 3) * 256;
    for (int i = slice * 256 + threadIdx.x; i < E; i += stride) {
        int s = src[i], d = dst[i];
        s = (s < 0) ? 0 : ((s >= N) ? N - 1 : s);
        d = (d < 0) ? 0 : ((d >= N) ? N - 1 : d);
        if (s >= lo && s < hi) { int p = atomicAdd(&cursor[s], 1); col[p] = d; }
        if (d >= lo && d < hi) { int q = atomicAdd(&cursor[d], 1); col[q] = s; }
    }
}

__global__ __launch_bounds__(256) void gather_csr2(
    const float* __restrict__ x, const float* __restrict__ epsp,
    const int* __restrict__ rowstart, const int* __restrict__ col,
    float* __restrict__ pre, int N)
{
    int wid = (blockIdx.x * 256 + threadIdx.x) >> 6;
    int lane = threadIdx.x & 63;
    int v0 = wid * 2;
    if (v0 >= N) return;
    int v1 = v0 + 1;
    float eps1 = 1.0f + epsp[0];
    int j0 = rowstart[v0], re0 = rowstart[v0 + 1];
    float a0 = eps1 * x[(size_t)v0 * D + lane];
    int j1 = 0, re1 = 0;
    float a1 = 0.0f;
    if (v1 < N) {
        j1 = rowstart[v1]; re1 = rowstart[v1 + 1];
        a1 = eps1 * x[(size_t)v1 * D + lane];
    }
    while (j0 + 8 <= re0 && j1 + 8 <= re1) {
        float p0 = x[(size_t)col[j0 + 0] * D + lane];
        float p1 = x[(size_t)col[j0 + 1] * D + lane];
        float p2 = x[(size_t)col[j0 + 2] * D + lane];
        float p3 = x[(size_t)col[j0 + 3] * D + lane];
        float p4 = x[(size_t)col[j0 + 4] * D + lane];
        float p5 = x[(size_t)col[j0 + 5] * D + lane];
        float p6 = x[(size_t)col[j0 + 6] * D + lane];
        float p7 = x[(size_t)col[j0 + 7] * D + lane];
        float q0 = x[(size_t)col[j1 + 0] * D + lane];
        float q1 = x[(size_t)col[j1 + 1] * D + lane];
        float q2 = x[(size_t)col[j1 + 2] * D + lane];
        float q3 = x[(size_t)col[j1 + 3] * D + lane];
        float q4 = x[(size_t)col[j1 + 4] * D + lane];
        float q5 = x[(size_t)col[j1 + 5] * D + lane];
        float q6 = x[(size_t)col[j1 + 6] * D + lane];
        float q7 = x[(size_t)col[j1 + 7] * D + lane];
        a0 += ((p0 + p1) + (p2 + p3)) + ((p4 + p5) + (p6 + p7));
        a1 += ((q0 + q1) + (q2 + q3)) + ((q4 + q5) + (q6 + q7));
        j0 += 8; j1 += 8;
    }
    for (; j0 + 8 <= re0; j0 += 8) {
        float p0 = x[(size_t)col[j0 + 0] * D + lane];
        float p1 = x[(size_t)col[j0 + 1] * D + lane];
        float p2 = x[(size_t)col[j0 + 2] * D + lane];
        float p3 = x[(size_t)col[j0 + 3] * D + lane];
        float p4 = x[(size_t)col[j0 + 4] * D + lane];
        float p5 = x[(size_t)col[j0 + 5] * D + lane];
        float p6 = x[(size_t)col[j0 + 6] * D + lane];
        float p7 = x[(size_t)col[j0 + 7] * D + lane];
        a0 += ((p0 + p1) + (p2 + p3)) + ((p4 + p5) + (p6 + p7));
    }
    for (; j1 + 8 <= re1; j1 += 8) {
        float q0 = x[(size_t)col[j1 + 0] * D + lane];
        float q1 = x[(size_t)col[j1 + 1] * D + lane];
        float q2 = x[(size_t)col[j1 + 2] * D + lane];
        float q3 = x[(size_t)col[j1 + 3] * D + lane];
        float q4 = x[(size_t)col[j1 + 4] * D + lane];
        float q5 = x[(size_t)col[j1 + 5] * D + lane];
        float q6 = x[(size_t)col[j1 + 6] * D + lane];
        float q7 = x[(size_t)col[j1 + 7] * D + lane];
        a1 += ((q0 + q1) + (q2 + q3)) + ((q4 + q5) + (q6 + q7));
    }
    for (; j0 < re0; ++j0) a0 += x[(size_t)col[j0] * D + lane];
    for (; j1 < re1; ++j1) a1 += x[(size_t)col[j1] * D + lane];
    pre[(size_t)v0 * D + lane] = a0;
    if (v1 < N) pre[(size_t)v1 * D + lane] = a1;
}

// Fallback VALU MLP (readlane), used by CSR/atomic paths only.
__device__ __forceinline__ void mlp_store(
    const float* acc, float* sW, int v0, int t, int lane, int nNodes,
    const float* __restrict__ W2,
    const float* __restrict__ b1, const float* __restrict__ b2,
    float* __restrict__ y)
{
    float b1a = b1[lane], b1b = b1[lane + 64];
    float ha[MPW], hb[MPW];
#pragma unroll
    for (int m = 0; m < MPW; ++m) { ha[m] = b1a; hb[m] = b1b; }
#pragma unroll 4
    for (int f = 0; f < D; ++f) {
        float wa = sW[f * H + lane];
        float wb = sW[f * H + lane + 64];
#pragma unroll
        for (int m = 0; m < MPW; ++m) {
            float o = lane_bcast(acc[m], f);
            ha[m] += o * wa;
            hb[m] += o * wb;
        }
    }
#pragma unroll
    for (int m = 0; m < MPW; ++m) {
        ha[m] = fmaxf(ha[m], 0.0f);
        hb[m] = fmaxf(hb[m], 0.0f);
    }

    __syncthreads();
    for (int i = t; i < H * D; i += 256) sW[i] = W2[i];
    __syncthreads();

    float b2v = b2[lane];
    float yv[MPW];
#pragma unroll
    for (int m = 0; m < MPW; ++m) yv[m] = b2v;
#pragma unroll 4
    for (int k = 0; k < 64; ++k) {
        float w = sW[k * D + lane];
#pragma unroll
        for (int m = 0; m < MPW; ++m) yv[m] += lane_bcast(ha[m], k) * w;
    }
#pragma unroll 4
    for (int k = 0; k < 64; ++k) {
        float w = sW[(k + 64) * D + lane];
#pragma unroll
        for (int m = 0; m < MPW; ++m) yv[m] += lane_bcast(hb[m], k) * w;
    }
#pragma unroll
    for (int m = 0; m < MPW; ++m) {
        int v = v0 + m;
        if (v < nNodes) y[(size_t)v * D + lane] = yv[m];
    }
}

__global__ __launch_bounds__(256) void mlp_pre(
    const float* __restrict__ pre, const float* __restrict__ W1,
    const float* __restrict__ b1, const float* __restrict__ W2,
    const float* __restrict__ b2, float* __restrict__ y, int nNodes)
{
    __shared__ float sW[D * H];
    int t = threadIdx.x;
    for (int i = t; i < D * H; i += 256) sW[i] = W1[i];
    __syncthreads();
    int wave = t >> 6, lane = t & 63;
    int v0 = (blockIdx.x * 4 + wave) * MPW;
    float acc[MPW];
#pragma unroll
    for (int m = 0; m < MPW; ++m) {
        int v = v0 + m;
        acc[m] = (v < nNodes) ? pre[(size_t)v * D + lane] : 0.0f;
    }
    mlp_store(acc, sW, v0, t, lane, nNodes, W2, b1, b2, y);
}

__global__ __launch_bounds__(256) void gather_mlp_csr(
    const float* __restrict__ x, const float* __restrict__ W1,
    const float* __restrict__ b1, const float* __restrict__ W2,
    const float* __restrict__ b2, const float* __restrict__ epsp,
    const int* __restrict__ rowstart, const int* __restrict__ col,
    float* __restrict__ y, int nNodes)
{
    __shared__ float sW[D * H];
    int t = threadIdx.x;
    for (int i = t; i < D * H; i += 256) sW[i] = W1[i];
    __syncthreads();
    int wave = t >> 6, lane = t & 63;
    float eps1 = 1.0f + epsp[0];
    int v0 = (blockIdx.x * 4 + wave) * MPW;
    float acc[MPW];
#pragma unroll
    for (int m = 0; m < MPW; ++m) {
        int v = v0 + m;
        float a = 0.0f;
        if (v < nNodes) {
            int rs = rowstart[v], re = rowstart[v + 1];
            a = eps1 * x[(size_t)v * D + lane];
            int j = rs;
            for (; j + 8 <= re; j += 8) {
                float p0 = x[(size_t)col[j + 0] * D + lane];
                float p1 = x[(size_t)col[j + 1] * D + lane];
                float p2 = x[(size_t)col[j + 2] * D + lane];
                float p3 = x[(size_t)col[j + 3] * D + lane];
                float p4 = x[(size_t)col[j + 4] * D + lane];
                float p5 = x[(size_t)col[j + 5] * D + lane];
                float p6 = x[(size_t)col[j + 6] * D + lane];
                float p7 = x[(size_t)col[j + 7] * D + lane];
                a += ((p0 + p1) + (p2 + p3)) + ((p4 + p5) + (p6 + p7));
            }
            for (; j < re; ++j) a += x[(size_t)col[j] * D + lane];
        }
        acc[m] = a;
    }
    mlp_store(acc, sW, v0, t, lane, nNodes, W2, b1, b2, y);
}

__global__ void scatter_kernel(const float* __restrict__ x,
                               const int* __restrict__ src,
                               const int* __restrict__ dst,
                               float* __restrict__ agg, int E, int N)
{
    int tid = blockIdx.x * blockDim.x + threadIdx.x;
    int e = tid >> 6, lane = tid & 63;
    if (e < E) {
        int s = src[e], d = dst[e];
        s = (s < 0) ? 0 : ((s >= N) ? N - 1 : s);
        d = (d < 0) ? 0 : ((d >= N) ? N - 1 : d);
        float xs = x[(size_t)s * D + lane];
        float xd = x[(size_t)d * D + lane];
        atomicAdd(&agg[(size_t)s * D + lane], xd);
        atomicAdd(&agg[(size_t)d * D + lane], xs);
    }
}

__global__ __launch_bounds__(256) void mlp_from_agg(
    const float* __restrict__ x, const float* __restrict__ W1,
    const float* __restrict__ b1, const float* __restrict__ W2,
    const float* __restrict__ b2, const float* __restrict__ epsp,
    float* __restrict__ yio, int nNodes)
{
    __shared__ float sW[D * H];
    int t = threadIdx.x;
    for (int i = t; i < D * H; i += 256) sW[i] = W1[i];
    __syncthreads();
    int wave = t >> 6, lane = t & 63;
    float eps1 = 1.0f + epsp[0];
    int v0 = (blockIdx.x * 4 + wave) * MPW;
    float acc[MPW];
#pragma unroll
    for (int m = 0; m < MPW; ++m) {
        int v = v0 + m;
        acc[m] = (v < nNodes)
                   ? (eps1 * x[(size_t)v * D + lane] + yio[(size_t)v * D + lane])
                   : 0.0f;
    }
    mlp_store(acc, sW, v0, t, lane, nNodes, W2, b1, b2, yio);
}

extern "C" void kernel_launch(void* const* d_in, const int* in_sizes, int n_in,
                              void* d_out, int out_size, void* d_ws, size_t ws_size,
                              hipStream_t stream)
{
    const float* x   = (const float*)d_in[0];
    const float* W1  = (const float*)d_in[1];
    const float* b1  = (const float*)d_in[2];
    const float* W2  = (const float*)d_in[3];
    const float* b2  = (const float*)d_in[4];
    const float* eps = (const float*)d_in[5];
    const int*   ei  = (const int*)d_in[6];
    float* out = (float*)d_out;

    int N = in_sizes[0] / D;
    int E = in_sizes[6] / 2;
    const int* src = ei;
    const int* dst = ei + E;

    int nb = (N + 255) / 256;

    // partition path ws: cursor(int NR) + evarr(u32 NR*CAPB)
    //                    + xh(u16 (N+1)*D) + wsW1/wsW2(u16 8192 each)
    int NR = (N + REGSZ - 1) >> REGSH;
    int meanE = (NR > 0) ? (2 * E + NR - 1) / NR : 0;
    int CAPB = meanE + meanE / 4 + 128;
    int EPB = (E + P1_BLOCKS - 1) / P1_BLOCKS;
    size_t off_cur  = 0;
    size_t off_ev   = (off_cur + (size_t)NR * 4 + 15) & ~(size_t)15;
    size_t off_xh   = (off_ev + (size_t)NR * CAPB * 4 + 15) & ~(size_t)15;
    size_t off_w1   = (off_xh + (size_t)(N + 1) * D * 2 + 15) & ~(size_t)15;
    size_t off_w2   = off_w1 + 8192 * 2;
    size_t need_part = off_w2 + 8192 * 2;

    size_t csr_ints = (size_t)(3 * N + 1 + 2 * E) + 512;
    size_t need_csr = csr_ints * sizeof(int);
    size_t need_split = need_csr + (size_t)N * D * sizeof(float);
    int mlp_blocks = (N + 4 * MPW - 1) / (4 * MPW);

    if (ws_size >= need_part && N >= REGSZ && N <= 65535
        && NR <= NR_MAX && 2 * EPB <= EVBUF_SZ && (N * D) % 2 == 0) {
        char* base = (char*)d_ws;
        int*            cursor = (int*)(base + off_cur);
        unsigned int*   evarr  = (unsigned int*)(base + off_ev);
        unsigned short* xh     = (unsigned short*)(base + off_xh);
        unsigned short* wsW1   = (unsigned short*)(base + off_w1);
        unsigned short* wsW2   = (unsigned short*)(base + off_w2);
        int npairs = N * D / 2;

        prep_kernel<<<32, 256, 0, stream>>>(
            (unsigned int*)xh, npairs, cursor, NR, CAPB, W1, W2, wsW1, wsW2);
        part1_kernel<<<P1_BLOCKS, 256, 0, stream>>>(
            src, dst, cursor, evarr, x, (unsigned int*)xh, npairs,
            E, N, NR, CAPB, EPB);
        part2_fused<<<NR, 1024, 0, stream>>>(
            evarr, cursor, xh, x, eps, wsW1, wsW2, b1, b2, out, N, CAPB);
    } else if (ws_size >= need_csr) {
        int*   deg      = (int*)d_ws;
        int*   cursor   = deg + N;
        int*   rowstart = cursor + N;
        int*   col      = rowstart + (N + 1);
        int*   bsum     = col + 2 * E;
        int*   boff     = bsum + 256;
        float* pre      = (float*)(boff + 256);

        zero_int_kernel<<<(N + 255) / 256, 256, 0, stream>>>(deg, N);
        count_kernel<<<(2 * E + 255) / 256, 256, 0, stream>>>(ei, deg, 2 * E, N);
        if (nb <= 256) {
            scan_part1<<<nb, 256, 0, stream>>>(deg, bsum, N);
            scan_part2<<<1, 256, 0, stream>>>(bsum, boff, &rowstart[N], nb);
            scan_part3<<<nb, 256, 0, stream>>>(deg, boff, rowstart, cursor, N);
        } else {
            int chunk = (N + 255) / 256;
            scan_single<<<1, 256, 0, stream>>>(deg, rowstart, cursor, N, chunk);
        }
        fill_xcd<<<2048, 256, 0, stream>>>(src, dst, cursor, col, E, N, (N + 7) / 8);
        int waves = (N + 1) / 2;
        int gather_blocks = (waves + 3) / 4;
        if (ws_size >= need_split) {
            gather_csr2<<<gather_blocks, 256, 0, stream>>>(x, eps, rowstart, col, pre, N);
            mlp_pre<<<mlp_blocks, 256, 0, stream>>>(pre, W1, b1, W2, b2, out, N);
        } else {
            gather_mlp_csr<<<mlp_blocks, 256, 0, stream>>>(
                x, W1, b1, W2, b2, eps, rowstart, col, out, N);
        }
    } else {
        int nd = N * D;
        zero_f_kernel<<<(nd + 255) / 256, 256, 0, stream>>>(out, nd);
        long long st = (long long)E * 64;
        scatter_kernel<<<(int)((st + 255) / 256), 256, 0, stream>>>(x, src, dst, out, E, N);
        mlp_from_agg<<<mlp_blocks, 256, 0, stream>>>(x, W1, b1, W2, b2, eps, out, N);
    }
}

// Round 11
// 134.582 us; speedup vs baseline: 1.0625x; 1.0625x over previous
//
#include <hip/hip_runtime.h>

// GINConv: out = MLP((1+eps)*x + neighbor_sum), MLP = 64->128 relu -> 64, fp32.
// Round 25: R24 regressed (141.5->143): part2 occ 41->56% but dur 46.6->50.7
// (bank conflicts 1.35M->2.16M, extra barrier, 4x redundant A-frags, scnt
// contention). REVERT part2 to R23's proven 512-thread form (46.6us).
// Remaining budget: total 141.5 - part2 46.6 - prep ~2 => part1 ~40-60us,
// and part1 runs at 256 blocks x 256 thr = 4 waves/CU (12.5% occ) while
// carrying the 19.2MB cast. Fix:
//  (a) cast moves part1 -> prep, prep launched at 1024 blocks (~4us).
//  (b) part1 at 256 blocks x 1024 threads (16 waves/CU, 50% occ; LDS
//      78.5KB fits). Same block count -> same ~200K global atomics.
//      Scan generalized to 1024-entry workspace (4 regions/thread).
// Prediction: part1 ~40-55 -> ~15-25us (may enter top-5), total ->118-128.
// If part1 unchanged -> atomic-reserve or edge-load bound -> REGSZ 128 next.
// Invariants: MFMA layouts HW-verified; weights direct-from-global (R23);
// hbuf aliases pre_lds (R23); no fp LDS atomics (R19); part1 sorted-
// coalesced scatter (R21); self-loops verified; dummy = zeroed xh row N;
// CSR/scatter fallbacks intact.

#define D 64
#define H 128
#define MPW 8            // nodes per wave in the fallback VALU MLP
#define REGSH 6          // region = 64 nodes (v >> 6)
#define REGSZ 64
#define P1_BLOCKS 256
#define P1_THREADS 1024
#define EVBUF_SZ 6400    // LDS event buffer in part1 (2*EPB must fit)
#define NR_MAX 1024
#define NCAP 96          // per-node LDS list capacity (Poisson(32): safe)
#define PSTR 68          // pre_lds row stride in floats (16B-aligned, 2-way)

typedef __attribute__((ext_vector_type(8))) short short8;   // 8 bf16 (4 VGPRs)
typedef __attribute__((ext_vector_type(4))) float float4v;  // 4 fp32

__device__ __forceinline__ float lane_bcast(float v, int l) {
    return __uint_as_float(__builtin_amdgcn_readlane(__float_as_uint(v), l));
}

__device__ __forceinline__ unsigned short f2bf(float f) {
    unsigned int u = __float_as_uint(f);
    u = (u + (((u >> 16) & 1u) + 0x7fffu)) >> 16;
    return (unsigned short)u;
}

__device__ __forceinline__ void bf2_acc(unsigned int u, float& a, float& b) {
    a += __uint_as_float(u << 16);            // low ushort  = feature 2h
    b += __uint_as_float(u & 0xffff0000u);    // high ushort = feature 2h+1
}

__global__ void zero_int_kernel(int* __restrict__ p, int n) {
    int i = blockIdx.x * blockDim.x + threadIdx.x;
    if (i < n) p[i] = 0;
}

__global__ void zero_f_kernel(float* __restrict__ p, int n) {
    int i = blockIdx.x * blockDim.x + threadIdx.x;
    if (i < n) p[i] = 0.0f;
}

// prep: x->bf16 cast (full-grid, ~4us) + init region cursors + zero dummy
// row N + swizzle weights. Launched at 1024 blocks.
__global__ void prep_kernel(const float* __restrict__ x,
                            unsigned int* __restrict__ xh2, int npairs,
                            int* __restrict__ cursor, int NR, int CAPB,
                            const float* __restrict__ W1,
                            const float* __restrict__ W2,
                            unsigned short* __restrict__ wsW1,
                            unsigned short* __restrict__ wsW2) {
    int i = blockIdx.x * blockDim.x + threadIdx.x;
    int gs = gridDim.x * blockDim.x;
    for (int k = i; k < npairs; k += gs) {
        float2 v = *(const float2*)(x + (size_t)k * 2);
        unsigned int a = __float_as_uint(v.x);
        unsigned int b = __float_as_uint(v.y);
        a = (a + (((a >> 16) & 1u) + 0x7fffu)) >> 16;
        b = (b + (((b >> 16) & 1u) + 0x7fffu)) >> 16;
        xh2[k] = a | (b << 16);
    }
    if (i < NR) cursor[i] = i * CAPB;
    if (i < 32) xh2[npairs + i] = 0;    // dummy row N (zero target)
    if (i < 8192) {
        int j = i & 7, ln = (i >> 3) & 63;
        int q = (ln >> 4) & 3;
        int tt1 = (i >> 9) & 7, s1 = i >> 12;
        wsW1[i] = f2bf(W1[(s1 * 32 + q * 8 + j) * H + tt1 * 16 + (ln & 15)]);
        int tt2 = (i >> 9) & 3, s2 = i >> 11;
        wsW2[i] = f2bf(W2[(s2 * 32 + q * 8 + j) * D + tt2 * 16 + (ln & 15)]);
    }
}

// ---- part1: region partition with sorted, coalesced output writes
// (R21-proven), now at 1024 threads/block (16 waves/CU, 50% occ).
__global__ __launch_bounds__(P1_THREADS) void part1_kernel(
    const int* __restrict__ src, const int* __restrict__ dst,
    int* __restrict__ cursor, unsigned int* __restrict__ evarr,
    int E, int N, int NR, int CAPB, int EPB)
{
    __shared__ unsigned int evbuf[EVBUF_SZ];        // 25.6KB raw events
    __shared__ unsigned int sortbuf[EVBUF_SZ];      // 25.6KB region-sorted
    __shared__ unsigned short tickbuf[EVBUF_SZ];    // 12.8KB per-event rank
    __shared__ int hist[NR_MAX];                    // 4KB per-region count
    __shared__ int lbase[NR_MAX];                   // 4KB local prefix base
    __shared__ int gbase[NR_MAX];                   // 4KB global chunk base
    __shared__ int scanw[P1_THREADS];               // 4KB scan workspace
    int t = threadIdx.x;

    for (int b = t; b < NR; b += P1_THREADS) hist[b] = 0;
    __syncthreads();

    // pass 1: load events, LDS histogram with per-event ticket
    int e0 = blockIdx.x * EPB;
    int ne = E - e0; if (ne > EPB) ne = EPB; if (ne < 0) ne = 0;
    for (int i = t; i < ne; i += P1_THREADS) {
        int s = src[e0 + i], d = dst[e0 + i];
        s = (s < 0) ? 0 : ((s >= N) ? N - 1 : s);
        d = (d < 0) ? 0 : ((d >= N) ? N - 1 : d);
        unsigned int ev0 = ((unsigned int)s << 16) | (unsigned int)d;
        unsigned int ev1 = ((unsigned int)d << 16) | (unsigned int)s;
        int k0 = atomicAdd(&hist[s >> REGSH], 1);
        int k1 = atomicAdd(&hist[d >> REGSH], 1);
        evbuf[2 * i]     = ev0; tickbuf[2 * i]     = (unsigned short)k0;
        evbuf[2 * i + 1] = ev1; tickbuf[2 * i + 1] = (unsigned short)k1;
    }
    __syncthreads();

    // exclusive prefix scan: hist -> lbase (1 entry per thread + block scan;
    // NR <= NR_MAX <= P1_THREADS)
    {
        int h0 = (t < NR) ? hist[t] : 0;
        scanw[t] = h0;
        __syncthreads();
        for (int off = 1; off < P1_THREADS; off <<= 1) {
            int u = (t >= off) ? scanw[t - off] : 0;
            __syncthreads();
            scanw[t] += u;
            __syncthreads();
        }
        if (t < NR) lbase[t] = scanw[t] - h0;   // exclusive
    }

    // reserve: one global atomic per nonzero region
    for (int b = t; b < NR; b += P1_THREADS) {
        int c = hist[b];
        gbase[b] = c ? atomicAdd(&cursor[b], c) : 0;
    }
    __syncthreads();

    // LDS reorder: sortbuf holds events grouped by region
    int nev = 2 * ne;
    for (int i = t; i < nev; i += P1_THREADS) {
        unsigned int ev = evbuf[i];
        int reg = (int)(ev >> (16 + REGSH));
        sortbuf[lbase[reg] + (int)tickbuf[i]] = ev;
    }
    __syncthreads();

    // coalesced global write: consecutive i -> consecutive addr per region run
    for (int i = t; i < nev; i += P1_THREADS) {
        unsigned int ev = sortbuf[i];
        int reg = (int)(ev >> (16 + REGSH));
        int addr = gbase[reg] + (i - lbase[reg]);
        if (addr < (reg + 1) * CAPB) evarr[addr] = ev;
    }
}

// ---- part2_fused (R23-proven 512-thread form): Phase A (bucket, int
// atomics) + Phase B (register gather) + MFMA MLP (weights direct from
// global; hbuf aliases pre_lds). LDS ~30KB -> 4 blocks/CU wave-capped.
__global__ __launch_bounds__(512, 8) void part2_fused(
    const unsigned int* __restrict__ evarr, const int* __restrict__ cursor,
    const unsigned short* __restrict__ xh, const float* __restrict__ x,
    const float* __restrict__ epsp,
    const unsigned short* __restrict__ wsW1,
    const unsigned short* __restrict__ wsW2,
    const float* __restrict__ b1, const float* __restrict__ b2,
    float* __restrict__ y, int N, int CAPB)
{
    __shared__ unsigned short nbuf[REGSZ * NCAP + 32];  // 12.1KB (+pad tail)
    __shared__ int scnt[REGSZ];                         // 256B
    __shared__ float pre_lds[REGSZ * PSTR];             // 17.4KB; hbuf aliases
    int t = threadIdx.x;
    int b = blockIdx.x;
    if (t < REGSZ) scnt[t] = 0;
    __syncthreads();

    int base = b * CAPB;
    int count = cursor[b] - base;
    if (count < 0) count = 0;
    if (count > CAPB) count = CAPB;

    // Phase A: bucket into per-node lists (int ticket + plain ds_write)
    for (int i = t; i < count; i += 512) {
        unsigned int ev = evarr[base + i];
        int row = (int)((ev >> 16) & (REGSZ - 1));
        int k = atomicAdd(&scnt[row], 1);
        if (k < NCAP) nbuf[row * NCAP + k] = (unsigned short)(ev & 0xffffu);
    }
    __syncthreads();

    // Phase B: 8 waves x 8 nodes, register accumulation -> pre_lds
    int wave = t >> 6, lane = t & 63;
    int r = lane >> 5;            // row slot 0..1
    int h = lane & 31;            // feature pair 2h, 2h+1
    float e1 = 1.0f + epsp[0];

    for (int k = 0; k < 8; ++k) {
        int n = wave * 8 + k;
        int v = b * REGSZ + n;
        int m = (v < N) ? scnt[n] : 0;
        m = (m > NCAP) ? NCAP : m;
        float f0 = 0.0f, f1 = 0.0f;
        for (int j = 0; j < m; j += 32) {
            int cc[16];
#pragma unroll
            for (int q = 0; q < 16; ++q) {
                int ii = j + 2 * q + r;
                int c = (int)nbuf[n * NCAP + ii];   // in-bounds via +32 pad
                cc[q] = (ii < m) ? c : N;           // dummy zero row past degree
            }
            unsigned int u[16];
#pragma unroll
            for (int q = 0; q < 16; ++q)
                u[q] = *(const unsigned int*)(xh + (size_t)cc[q] * D + 2 * h);
#pragma unroll
            for (int q = 0; q < 16; ++q) bf2_acc(u[q], f0, f1);
        }
        f0 += __shfl_xor(f0, 32, 64);
        f1 += __shfl_xor(f1, 32, 64);
        if (r == 0) {
            float2 sv = make_float2(0.0f, 0.0f);
            if (v < N) sv = *(const float2*)(x + (size_t)v * D + 2 * h);
            pre_lds[n * PSTR + 2 * h]     = f0 + e1 * sv.x;
            pre_lds[n * PSTR + 2 * h + 1] = f1 + e1 * sv.y;
        }
    }
    __syncthreads();

    // ---- MFMA MLP: tile p = wave>>1 (16 nodes), half hh = wave&1.
    int p = wave >> 1, hh = wave & 1;
    int quad = lane >> 4, lm = lane & 15;
    int row0 = p * 16 + lm;               // node-in-region this lane supplies

    short8 a1f[2];
#pragma unroll
    for (int s = 0; s < 2; ++s) {
        const float* rp = &pre_lds[row0 * PSTR + s * 32 + quad * 8];
        float4v p0 = *(const float4v*)rp;
        float4v p1 = *(const float4v*)(rp + 4);
        short8 a;
        a[0] = (short)f2bf(p0[0]); a[1] = (short)f2bf(p0[1]);
        a[2] = (short)f2bf(p0[2]); a[3] = (short)f2bf(p0[3]);
        a[4] = (short)f2bf(p1[0]); a[5] = (short)f2bf(p1[1]);
        a[6] = (short)f2bf(p1[2]); a[7] = (short)f2bf(p1[3]);
        a1f[s] = a;
    }
    __syncthreads();    // all pre_lds reads done -> safe to alias as hbuf

    unsigned short* hbuf = (unsigned short*)pre_lds;  // 16KB used of 17.4KB

    // GEMM1: this wave computes h-columns tt = hh*4 .. hh*4+3
    float4v acc1[4];
#pragma unroll
    for (int i = 0; i < 4; ++i) {
        int tt = hh * 4 + i;
        float bb = b1[tt * 16 + lm];
        float4v c = {bb, bb, bb, bb};
#pragma unroll
        for (int s = 0; s < 2; ++s) {
            short8 bw = *(const short8*)&wsW1[((s * 8 + tt) * 64 + lane) * 8];
            c = __builtin_amdgcn_mfma_f32_16x16x32_bf16(a1f[s], bw, c, 0, 0, 0);
        }
        acc1[i] = c;
    }

    unsigned short* hb = &hbuf[p * 16 * H];
#pragma unroll
    for (int i = 0; i < 4; ++i) {
        int tt = hh * 4 + i;
#pragma unroll
        for (int rr = 0; rr < 4; ++rr) {
            float hv = fmaxf(acc1[i][rr], 0.0f);
            hb[(quad * 4 + rr) * H + tt * 16 + lm] = f2bf(hv);
        }
    }
    __syncthreads();

    short8 a2[4];
#pragma unroll
    for (int s = 0; s < 4; ++s)
        a2[s] = *(const short8*)&hb[lm * H + s * 32 + quad * 8];

    // GEMM2: this wave computes y-columns tt = hh*2 .. hh*2+1
    int v0t = b * REGSZ + p * 16;
#pragma unroll
    for (int i = 0; i < 2; ++i) {
        int tt = hh * 2 + i;
        float bb = b2[tt * 16 + lm];
        float4v c = {bb, bb, bb, bb};
#pragma unroll
        for (int s = 0; s < 4; ++s) {
            short8 bw = *(const short8*)&wsW2[((s * 4 + tt) * 64 + lane) * 8];
            c = __builtin_amdgcn_mfma_f32_16x16x32_bf16(a2[s], bw, c, 0, 0, 0);
        }
#pragma unroll
        for (int rr = 0; rr < 4; ++rr) {
            int v = v0t + quad * 4 + rr;
            if (v < N) y[(size_t)v * D + tt * 16 + lm] = c[rr];
        }
    }
}

// ================= CSR machinery (fallback paths, fp32) =================

__global__ void count_kernel(const int* __restrict__ ei, int* __restrict__ deg,
                             int twoE, int N) {
    int i = blockIdx.x * blockDim.x + threadIdx.x;
    if (i < twoE) {
        int v = ei[i];
        v = (v < 0) ? 0 : ((v >= N) ? N - 1 : v);
        atomicAdd(&deg[v], 1);
    }
}

__global__ __launch_bounds__(256) void scan_part1(const int* __restrict__ deg,
                                                  int* __restrict__ bsum, int n) {
    __shared__ int red[256];
    int t = threadIdx.x;
    int i = blockIdx.x * 256 + t;
    red[t] = (i < n) ? deg[i] : 0;
    __syncthreads();
    for (int off = 128; off > 0; off >>= 1) {
        if (t < off) red[t] += red[t + off];
        __syncthreads();
    }
    if (t == 0) bsum[blockIdx.x] = red[0];
}

__global__ __launch_bounds__(256) void scan_part2(const int* __restrict__ bsum,
                                                  int* __restrict__ boff,
                                                  int* __restrict__ rowstart_n, int nb) {
    __shared__ int s[256];
    int t = threadIdx.x;
    int v = (t < nb) ? bsum[t] : 0;
    s[t] = v;
    __syncthreads();
    for (int off = 1; off < 256; off <<= 1) {
        int u = (t >= off) ? s[t - off] : 0;
        __syncthreads();
        s[t] += u;
        __syncthreads();
    }
    if (t < nb) boff[t] = s[t] - v;
    if (t == 255) *rowstart_n = s[255];
}

__global__ __launch_bounds__(256) void scan_part3(const int* __restrict__ deg,
                                                  const int* __restrict__ boff,
                                                  int* __restrict__ rowstart,
                                                  int* __restrict__ cursor, int n) {
    __shared__ int s[256];
    int t = threadIdx.x;
    int i = blockIdx.x * 256 + t;
    int v = (i < n) ? deg[i] : 0;
    s[t] = v;
    __syncthreads();
    for (int off = 1; off < 256; off <<= 1) {
        int u = (t >= off) ? s[t - off] : 0;
        __syncthreads();
        s[t] += u;
        __syncthreads();
    }
    if (i < n) {
        int r = boff[blockIdx.x] + s[t] - v;
        rowstart[i] = r;
        cursor[i] = r;
    }
}

__global__ __launch_bounds__(256) void scan_single(const int* __restrict__ deg,
                                                   int* __restrict__ rowstart,
                                                   int* __restrict__ cursor,
                                                   int n, int chunk) {
    __shared__ int psum[256];
    int t = threadIdx.x;
    int lo = t * chunk;
    int hi = lo + chunk; if (hi > n) hi = n;
    int s = 0;
    for (int i = lo; i < hi; ++i) s += deg[i];
    psum[t] = s;
    __syncthreads();
    for (int off = 1; off < 256; off <<= 1) {
        int v = (t >= off) ? psum[t - off] : 0;
        __syncthreads();
        psum[t] += v;
        __syncthreads();
    }
    int run = (t == 0) ? 0 : psum[t - 1];
    for (int i = lo; i < hi; ++i) {
        int d = deg[i];
        rowstart[i] = run;
        cursor[i] = run;
        run += d;
    }
    if (t == 255) rowstart[n] = psum[255];
}

__global__ __launch_bounds__(256) void fill_xcd(
    const int* __restrict__ src, const int* __restrict__ dst,
    int* __restrict__ cursor, int* __restrict__ col,
    int E, int N, int npg)
{
    int grp = blockIdx.x & 7;
    int slice = blockIdx.x >> 3;
    int lo = grp * npg;
    int hi = lo + npg; if (hi > N) hi = N;
    int stride = (gridDim.x >> 3) * 256;
    for (int i = slice * 256 + threadIdx.x; i < E; i += stride) {
        int s = src[i], d = dst[i];
        s = (s < 0) ? 0 : ((s >= N) ? N - 1 : s);
        d = (d < 0) ? 0 : ((d >= N) ? N - 1 : d);
        if (s >= lo && s < hi) { int p = atomicAdd(&cursor[s], 1); col[p] = d; }
        if (d >= lo && d < hi) { int q = atomicAdd(&cursor[d], 1); col[q] = s; }
    }
}

__global__ __launch_bounds__(256) void gather_csr2(
    const float* __restrict__ x, const float* __restrict__ epsp,
    const int* __restrict__ rowstart, const int* __restrict__ col,
    float* __restrict__ pre, int N)
{
    int wid = (blockIdx.x * 256 + threadIdx.x) >> 6;
    int lane = threadIdx.x & 63;
    int v0 = wid * 2;
    if (v0 >= N) return;
    int v1 = v0 + 1;
    float eps1 = 1.0f + epsp[0];
    int j0 = rowstart[v0], re0 = rowstart[v0 + 1];
    float a0 = eps1 * x[(size_t)v0 * D + lane];
    int j1 = 0, re1 = 0;
    float a1 = 0.0f;
    if (v1 < N) {
        j1 = rowstart[v1]; re1 = rowstart[v1 + 1];
        a1 = eps1 * x[(size_t)v1 * D + lane];
    }
    while (j0 + 8 <= re0 && j1 + 8 <= re1) {
        float p0 = x[(size_t)col[j0 + 0] * D + lane];
        float p1 = x[(size_t)col[j0 + 1] * D + lane];
        float p2 = x[(size_t)col[j0 + 2] * D + lane];
        float p3 = x[(size_t)col[j0 + 3] * D + lane];
        float p4 = x[(size_t)col[j0 + 4] * D + lane];
        float p5 = x[(size_t)col[j0 + 5] * D + lane];
        float p6 = x[(size_t)col[j0 + 6] * D + lane];
        float p7 = x[(size_t)col[j0 + 7] * D + lane];
        float q0 = x[(size_t)col[j1 + 0] * D + lane];
        float q1 = x[(size_t)col[j1 + 1] * D + lane];
        float q2 = x[(size_t)col[j1 + 2] * D + lane];
        float q3 = x[(size_t)col[j1 + 3] * D + lane];
        float q4 = x[(size_t)col[j1 + 4] * D + lane];
        float q5 = x[(size_t)col[j1 + 5] * D + lane];
        float q6 = x[(size_t)col[j1 + 6] * D + lane];
        float q7 = x[(size_t)col[j1 + 7] * D + lane];
        a0 += ((p0 + p1) + (p2 + p3)) + ((p4 + p5) + (p6 + p7));
        a1 += ((q0 + q1) + (q2 + q3)) + ((q4 + q5) + (q6 + q7));
        j0 += 8; j1 += 8;
    }
    for (; j0 + 8 <= re0; j0 += 8) {
        float p0 = x[(size_t)col[j0 + 0] * D + lane];
        float p1 = x[(size_t)col[j0 + 1] * D + lane];
        float p2 = x[(size_t)col[j0 + 2] * D + lane];
        float p3 = x[(size_t)col[j0 + 3] * D + lane];
        float p4 = x[(size_t)col[j0 + 4] * D + lane];
        float p5 = x[(size_t)col[j0 + 5] * D + lane];
        float p6 = x[(size_t)col[j0 + 6] * D + lane];
        float p7 = x[(size_t)col[j0 + 7] * D + lane];
        a0 += ((p0 + p1) + (p2 + p3)) + ((p4 + p5) + (p6 + p7));
    }
    for (; j1 + 8 <= re1; j1 += 8) {
        float q0 = x[(size_t)col[j1 + 0] * D + lane];
        float q1 = x[(size_t)col[j1 + 1] * D + lane];
        float q2 = x[(size_t)col[j1 + 2] * D + lane];
        float q3 = x[(size_t)col[j1 + 3] * D + lane];
        float q4 = x[(size_t)col[j1 + 4] * D + lane];
        float q5 = x[(size_t)col[j1 + 5] * D + lane];
        float q6 = x[(size_t)col[j1 + 6] * D + lane];
        float q7 = x[(size_t)col[j1 + 7] * D + lane];
        a1 += ((q0 + q1) + (q2 + q3)) + ((q4 + q5) + (q6 + q7));
    }
    for (; j0 < re0; ++j0) a0 += x[(size_t)col[j0] * D + lane];
    for (; j1 < re1; ++j1) a1 += x[(size_t)col[j1] * D + lane];
    pre[(size_t)v0 * D + lane] = a0;
    if (v1 < N) pre[(size_t)v1 * D + lane] = a1;
}

// Fallback VALU MLP (readlane), used by CSR/atomic paths only.
__device__ __forceinline__ void mlp_store(
    const float* acc, float* sW, int v0, int t, int lane, int nNodes,
    const float* __restrict__ W2,
    const float* __restrict__ b1, const float* __restrict__ b2,
    float* __restrict__ y)
{
    float b1a = b1[lane], b1b = b1[lane + 64];
    float ha[MPW], hb[MPW];
#pragma unroll
    for (int m = 0; m < MPW; ++m) { ha[m] = b1a; hb[m] = b1b; }
#pragma unroll 4
    for (int f = 0; f < D; ++f) {
        float wa = sW[f * H + lane];
        float wb = sW[f * H + lane + 64];
#pragma unroll
        for (int m = 0; m < MPW; ++m) {
            float o = lane_bcast(acc[m], f);
            ha[m] += o * wa;
            hb[m] += o * wb;
        }
    }
#pragma unroll
    for (int m = 0; m < MPW; ++m) {
        ha[m] = fmaxf(ha[m], 0.0f);
        hb[m] = fmaxf(hb[m], 0.0f);
    }

    __syncthreads();
    for (int i = t; i < H * D; i += 256) sW[i] = W2[i];
    __syncthreads();

    float b2v = b2[lane];
    float yv[MPW];
#pragma unroll
    for (int m = 0; m < MPW; ++m) yv[m] = b2v;
#pragma unroll 4
    for (int k = 0; k < 64; ++k) {
        float w = sW[k * D + lane];
#pragma unroll
        for (int m = 0; m < MPW; ++m) yv[m] += lane_bcast(ha[m], k) * w;
    }
#pragma unroll 4
    for (int k = 0; k < 64; ++k) {
        float w = sW[(k + 64) * D + lane];
#pragma unroll
        for (int m = 0; m < MPW; ++m) yv[m] += lane_bcast(hb[m], k) * w;
    }
#pragma unroll
    for (int m = 0; m < MPW; ++m) {
        int v = v0 + m;
        if (v < nNodes) y[(size_t)v * D + lane] = yv[m];
    }
}

__global__ __launch_bounds__(256) void mlp_pre(
    const float* __restrict__ pre, const float* __restrict__ W1,
    const float* __restrict__ b1, const float* __restrict__ W2,
    const float* __restrict__ b2, float* __restrict__ y, int nNodes)
{
    __shared__ float sW[D * H];
    int t = threadIdx.x;
    for (int i = t; i < D * H; i += 256) sW[i] = W1[i];
    __syncthreads();
    int wave = t >> 6, lane = t & 63;
    int v0 = (blockIdx.x * 4 + wave) * MPW;
    float acc[MPW];
#pragma unroll
    for (int m = 0; m < MPW; ++m) {
        int v = v0 + m;
        acc[m] = (v < nNodes) ? pre[(size_t)v * D + lane] : 0.0f;
    }
    mlp_store(acc, sW, v0, t, lane, nNodes, W2, b1, b2, y);
}

__global__ __launch_bounds__(256) void gather_mlp_csr(
    const float* __restrict__ x, const float* __restrict__ W1,
    const float* __restrict__ b1, const float* __restrict__ W2,
    const float* __restrict__ b2, const float* __restrict__ epsp,
    const int* __restrict__ rowstart, const int* __restrict__ col,
    float* __restrict__ y, int nNodes)
{
    __shared__ float sW[D * H];
    int t = threadIdx.x;
    for (int i = t; i < D * H; i += 256) sW[i] = W1[i];
    __syncthreads();
    int wave = t >> 6, lane = t & 63;
    float eps1 = 1.0f + epsp[0];
    int v0 = (blockIdx.x * 4 + wave) * MPW;
    float acc[MPW];
#pragma unroll
    for (int m = 0; m < MPW; ++m) {
        int v = v0 + m;
        float a = 0.0f;
        if (v < nNodes) {
            int rs = rowstart[v], re = rowstart[v + 1];
            a = eps1 * x[(size_t)v * D + lane];
            int j = rs;
            for (; j + 8 <= re; j += 8) {
                float p0 = x[(size_t)col[j + 0] * D + lane];
                float p1 = x[(size_t)col[j + 1] * D + lane];
                float p2 = x[(size_t)col[j + 2] * D + lane];
                float p3 = x[(size_t)col[j + 3] * D + lane];
                float p4 = x[(size_t)col[j + 4] * D + lane];
                float p5 = x[(size_t)col[j + 5] * D + lane];
                float p6 = x[(size_t)col[j + 6] * D + lane];
                float p7 = x[(size_t)col[j + 7] * D + lane];
                a += ((p0 + p1) + (p2 + p3)) + ((p4 + p5) + (p6 + p7));
            }
            for (; j < re; ++j) a += x[(size_t)col[j] * D + lane];
        }
        acc[m] = a;
    }
    mlp_store(acc, sW, v0, t, lane, nNodes, W2, b1, b2, y);
}

__global__ void scatter_kernel(const float* __restrict__ x,
                               const int* __restrict__ src,
                               const int* __restrict__ dst,
                               float* __restrict__ agg, int E, int N)
{
    int tid = blockIdx.x * blockDim.x + threadIdx.x;
    int e = tid >> 6, lane = tid & 63;
    if (e < E) {
        int s = src[e], d = dst[e];
        s = (s < 0) ? 0 : ((s >= N) ? N - 1 : s);
        d = (d < 0) ? 0 : ((d >= N) ? N - 1 : d);
        float xs = x[(size_t)s * D + lane];
        float xd = x[(size_t)d * D + lane];
        atomicAdd(&agg[(size_t)s * D + lane], xd);
        atomicAdd(&agg[(size_t)d * D + lane], xs);
    }
}

__global__ __launch_bounds__(256) void mlp_from_agg(
    const float* __restrict__ x, const float* __restrict__ W1,
    const float* __restrict__ b1, const float* __restrict__ W2,
    const float* __restrict__ b2, const float* __restrict__ epsp,
    float* __restrict__ yio, int nNodes)
{
    __shared__ float sW[D * H];
    int t = threadIdx.x;
    for (int i = t; i < D * H; i += 256) sW[i] = W1[i];
    __syncthreads();
    int wave = t >> 6, lane = t & 63;
    float eps1 = 1.0f + epsp[0];
    int v0 = (blockIdx.x * 4 + wave) * MPW;
    float acc[MPW];
#pragma unroll
    for (int m = 0; m < MPW; ++m) {
        int v = v0 + m;
        acc[m] = (v < nNodes)
                   ? (eps1 * x[(size_t)v * D + lane] + yio[(size_t)v * D + lane])
                   : 0.0f;
    }
    mlp_store(acc, sW, v0, t, lane, nNodes, W2, b1, b2, yio);
}

extern "C" void kernel_launch(void* const* d_in, const int* in_sizes, int n_in,
                              void* d_out, int out_size, void* d_ws, size_t ws_size,
                              hipStream_t stream)
{
    const float* x   = (const float*)d_in[0];
    const float* W1  = (const float*)d_in[1];
    const float* b1  = (const float*)d_in[2];
    const float* W2  = (const float*)d_in[3];
    const float* b2  = (const float*)d_in[4];
    const float* eps = (const float*)d_in[5];
    const int*   ei  = (const int*)d_in[6];
    float* out = (float*)d_out;

    int N = in_sizes[0] / D;
    int E = in_sizes[6] / 2;
    const int* src = ei;
    const int* dst = ei + E;

    int nb = (N + 255) / 256;

    // partition path ws: cursor(int NR) + evarr(u32 NR*CAPB)
    //                    + xh(u16 (N+1)*D) + wsW1/wsW2(u16 8192 each)
    int NR = (N + REGSZ - 1) >> REGSH;
    int meanE = (NR > 0) ? (2 * E + NR - 1) / NR : 0;
    int CAPB = meanE + meanE / 4 + 128;
    int EPB = (E + P1_BLOCKS - 1) / P1_BLOCKS;
    size_t off_cur  = 0;
    size_t off_ev   = (off_cur + (size_t)NR * 4 + 15) & ~(size_t)15;
    size_t off_xh   = (off_ev + (size_t)NR * CAPB * 4 + 15) & ~(size_t)15;
    size_t off_w1   = (off_xh + (size_t)(N + 1) * D * 2 + 15) & ~(size_t)15;
    size_t off_w2   = off_w1 + 8192 * 2;
    size_t need_part = off_w2 + 8192 * 2;

    size_t csr_ints = (size_t)(3 * N + 1 + 2 * E) + 512;
    size_t need_csr = csr_ints * sizeof(int);
    size_t need_split = need_csr + (size_t)N * D * sizeof(float);
    int mlp_blocks = (N + 4 * MPW - 1) / (4 * MPW);

    if (ws_size >= need_part && N >= REGSZ && N <= 65535
        && NR <= NR_MAX && 2 * EPB <= EVBUF_SZ && (N * D) % 2 == 0) {
        char* base = (char*)d_ws;
        int*            cursor = (int*)(base + off_cur);
        unsigned int*   evarr  = (unsigned int*)(base + off_ev);
        unsigned short* xh     = (unsigned short*)(base + off_xh);
        unsigned short* wsW1   = (unsigned short*)(base + off_w1);
        unsigned short* wsW2   = (unsigned short*)(base + off_w2);
        int npairs = N * D / 2;

        prep_kernel<<<1024, 256, 0, stream>>>(
            x, (unsigned int*)xh, npairs, cursor, NR, CAPB, W1, W2, wsW1, wsW2);
        part1_kernel<<<P1_BLOCKS, P1_THREADS, 0, stream>>>(
            src, dst, cursor, evarr, E, N, NR, CAPB, EPB);
        part2_fused<<<NR, 512, 0, stream>>>(
            evarr, cursor, xh, x, eps, wsW1, wsW2, b1, b2, out, N, CAPB);
    } else if (ws_size >= need_csr) {
        int*   deg      = (int*)d_ws;
        int*   cursor   = deg + N;
        int*   rowstart = cursor + N;
        int*   col      = rowstart + (N + 1);
        int*   bsum     = col + 2 * E;
        int*   boff     = bsum + 256;
        float* pre      = (float*)(boff + 256);

        zero_int_kernel<<<(N + 255) / 256, 256, 0, stream>>>(deg, N);
        count_kernel<<<(2 * E + 255) / 256, 256, 0, stream>>>(ei, deg, 2 * E, N);
        if (nb <= 256) {
            scan_part1<<<nb, 256, 0, stream>>>(deg, bsum, N);
            scan_part2<<<1, 256, 0, stream>>>(bsum, boff, &rowstart[N], nb);
            scan_part3<<<nb, 256, 0, stream>>>(deg, boff, rowstart, cursor, N);
        } else {
            int chunk = (N + 255) / 256;
            scan_single<<<1, 256, 0, stream>>>(deg, rowstart, cursor, N, chunk);
        }
        fill_xcd<<<2048, 256, 0, stream>>>(src, dst, cursor, col, E, N, (N + 7) / 8);
        int waves = (N + 1) / 2;
        int gather_blocks = (waves + 3) / 4;
        if (ws_size >= need_split) {
            gather_csr2<<<gather_blocks, 256, 0, stream>>>(x, eps, rowstart, col, pre, N);
            mlp_pre<<<mlp_blocks, 256, 0, stream>>>(pre, W1, b1, W2, b2, out, N);
        } else {
            gather_mlp_csr<<<mlp_blocks, 256, 0, stream>>>(
                x, W1, b1, W2, b2, eps, rowstart, col, out, N);
        }
    } else {
        int nd = N * D;
        zero_f_kernel<<<(nd + 255) / 256, 256, 0, stream>>>(out, nd);
        long long st = (long long)E * 64;
        scatter_kernel<<<(int)((st + 255) / 256), 256, 0, stream>>>(x, src, dst, out, E, N);
        mlp_from_agg<<<mlp_blocks, 256, 0, stream>>>(x, W1, b1, W2, b2, eps, out, N);
    }
}